// Round 1
// baseline (5218.361 us; speedup 1.0000x reference)
//
#include <hip/hip_runtime.h>

#define H 96
#define W 96
#define CIN 1024
#define NPIX 9216          // 96*96
#define NCH 54             // 18 cls + 36 reg channels
#define NA 82944           // 9216*9 anchors
#define TOPN 6000
#define NW 94              // ceil(6000/64)
#define POSN 300
#define CAND_CAP 8192

// ---------------------------------------------------------------------------
// init: accum <- bias (conv partials added atomically later), hist/ctrl <- 0
// ---------------------------------------------------------------------------
__global__ void k_init(const float* __restrict__ b_cls, const float* __restrict__ b_reg,
                       float* __restrict__ accum, unsigned int* __restrict__ hist,
                       unsigned int* __restrict__ ctrl) {
    int t = blockIdx.x * 256 + threadIdx.x;
    if (t < NPIX * NCH) {
        int ch = t % NCH;
        accum[t] = (ch < 18) ? b_cls[ch] : b_reg[ch - 18];
    } else if (t < NPIX * NCH + 65536) {
        hist[t - NPIX * NCH] = 0u;
    } else if (t < NPIX * NCH + 65536 + 16) {
        ctrl[t - NPIX * NCH - 65536] = 0u;
    }
}

// ---------------------------------------------------------------------------
// fused conv3x3(1024->512)+bias+relu  +  conv1x1 partials (54 ch) -> atomicAdd
// grid (8 co-blocks, 96 rows), 128 threads. thread = 4 co x 12 x.
// ---------------------------------------------------------------------------
__global__ __launch_bounds__(128) void k_conv(const float* __restrict__ x,
                                              const float* __restrict__ wr,
                                              const float* __restrict__ br,
                                              const float* __restrict__ wcl,
                                              const float* __restrict__ wrg,
                                              float* __restrict__ accum) {
    __shared__ float lds[9728];
    const int tid = threadIdx.x;
    const int cb = blockIdx.x;   // co block: 64 channels
    const int y  = blockIdx.y;   // output row
    const int tx = tid & 7;      // 8 x-groups of 12
    const int tc = tid >> 3;     // 16 co-groups of 4
    const int x0 = tx * 12;

    float acc[4][12];
#pragma unroll
    for (int c = 0; c < 4; ++c)
#pragma unroll
        for (int i = 0; i < 12; ++i) acc[c][i] = 0.f;

    float* xs = lds;           // [8 ci][3 rows][100] padded (idx = xx+1), pads zero
    float* wc = lds + 2400;    // [ci][ky][co 64][4] (kx in .x/.y/.z, .w unused)

    // zero the pad columns once (cols 0,97,98,99 of each of 24 rows)
    for (int i = tid; i < 96; i += 128) {
        int row = i >> 2, p = i & 3;
        int col = (p == 0) ? 0 : (96 + p);
        xs[row * 100 + col] = 0.f;
    }
    __syncthreads();

    for (int cc = 0; cc < CIN / 8; ++cc) {
        const int ci0 = cc * 8;
        for (int i = tid; i < 2304; i += 128) {           // 8*3*96 interior
            int ci = i / 288; int rem = i - ci * 288;
            int r = rem / 96; int xx = rem - r * 96;
            int yy = y + r - 1;
            float v = 0.f;
            if (yy >= 0 && yy < H) v = x[(ci0 + ci) * NPIX + yy * W + xx];
            xs[(ci * 3 + r) * 100 + xx + 1] = v;
        }
        for (int i = tid; i < 4608; i += 128) {           // 64co*8ci*9
            int co = i / 72; int rem = i - co * 72;
            int ci = rem / 9; int k = rem - ci * 9;
            int ky = k / 3, kx = k - ky * 3;
            wc[((ci * 3 + ky) * 64 + co) * 4 + kx] =
                wr[(cb * 64 + co) * (CIN * 9) + (ci0 + ci) * 9 + k];
        }
        __syncthreads();
#pragma unroll
        for (int ci = 0; ci < 8; ++ci) {
#pragma unroll
            for (int r = 0; r < 3; ++r) {
                const float* xrow = &xs[(ci * 3 + r) * 100 + x0];
                float4 xa = ((const float4*)xrow)[0];
                float4 xb = ((const float4*)xrow)[1];
                float4 xc = ((const float4*)xrow)[2];
                float4 xd = ((const float4*)xrow)[3];
                float xr[16] = {xa.x, xa.y, xa.z, xa.w, xb.x, xb.y, xb.z, xb.w,
                                xc.x, xc.y, xc.z, xc.w, xd.x, xd.y, xd.z, xd.w};
                const float4* wrow = (const float4*)&wc[((ci * 3 + r) * 64 + tc * 4) * 4];
                float4 w0 = wrow[0], w1 = wrow[1], w2 = wrow[2], w3 = wrow[3];
#pragma unroll
                for (int i2 = 0; i2 < 12; ++i2) {
                    acc[0][i2] += w0.x * xr[i2] + w0.y * xr[i2 + 1] + w0.z * xr[i2 + 2];
                    acc[1][i2] += w1.x * xr[i2] + w1.y * xr[i2 + 1] + w1.z * xr[i2 + 2];
                    acc[2][i2] += w2.x * xr[i2] + w2.y * xr[i2 + 1] + w2.z * xr[i2 + 2];
                    acc[3][i2] += w3.x * xr[i2] + w3.y * xr[i2 + 1] + w3.z * xr[i2 + 2];
                }
            }
        }
        __syncthreads();
    }

    // ---- epilogue: relu(h) tile -> LDS, 1x1 conv partials -> atomicAdd ----
    float* hs  = lds;         // [64][97] (+1 pad: bank-conflict break)
    float* wcs = lds + 6208;  // [54][65]
#pragma unroll
    for (int c = 0; c < 4; ++c) {
        float b = br[cb * 64 + tc * 4 + c];
#pragma unroll
        for (int i2 = 0; i2 < 12; ++i2)
            hs[(tc * 4 + c) * 97 + x0 + i2] = fmaxf(acc[c][i2] + b, 0.f);
    }
    for (int i = tid; i < NCH * 64; i += 128) {
        int ch = i >> 6, co = i & 63;
        float v = (ch < 18) ? wcl[ch * 512 + cb * 64 + co]
                            : wrg[(ch - 18) * 512 + cb * 64 + co];
        wcs[ch * 65 + co] = v;
    }
    __syncthreads();
    for (int i = tid; i < 96 * NCH; i += 128) {
        int px = i / NCH, ch = i - px * NCH;
        float s = 0.f;
#pragma unroll 4
        for (int co = 0; co < 64; ++co) s += hs[co * 97 + px] * wcs[ch * 65 + co];
        atomicAdd(&accum[(y * 96 + px) * NCH + ch], s);
    }
}

// ---------------------------------------------------------------------------
// decode: anchors + reg -> proposals/clipped boxes; cls -> d = c1-c0; histogram
// ---------------------------------------------------------------------------
__device__ __forceinline__ unsigned int key_of(float d) {
    unsigned int u = __float_as_uint(d);
    unsigned int k = (u & 0x80000000u) ? ~u : (u | 0x80000000u);  // asc in d
    return ~k;                                                     // asc key = desc d
}

__global__ void k_decode(const float* __restrict__ accum, const float* __restrict__ anchors,
                         float* __restrict__ props, float* __restrict__ boxes,
                         float* __restrict__ cls2, float* __restrict__ dval,
                         unsigned int* __restrict__ hist) {
    int idx = blockIdx.x * 256 + threadIdx.x;
    if (idx >= NA) return;
    int p = idx / 9, a = idx - p * 9;
    const float* ac = accum + p * NCH;
    float c0 = ac[2 * a], c1 = ac[2 * a + 1];
    float r0 = ac[18 + 4 * a + 0], r1 = ac[18 + 4 * a + 1];
    float r2 = ac[18 + 4 * a + 2], r3 = ac[18 + 4 * a + 3];
    const float* A = anchors + (size_t)idx * 4;
    float aw = A[2] - A[0] + 1.f, ah = A[3] - A[1] + 1.f;
    float ax = A[0] + 0.5f * (aw - 1.f), ay = A[1] + 0.5f * (ah - 1.f);
    float px = ax + aw * r0, py = ay + ah * r1;
    float pw = aw * expf(r2), ph = ah * expf(r3);
    float p0 = px - 0.5f * (pw - 1.f), p1 = py - 0.5f * (ph - 1.f);
    float p2 = px + 0.5f * (pw - 1.f), p3 = py + 0.5f * (ph - 1.f);
    props[idx * 4 + 0] = p0; props[idx * 4 + 1] = p1;
    props[idx * 4 + 2] = p2; props[idx * 4 + 3] = p3;
    boxes[idx * 4 + 0] = fminf(fmaxf(p0, 0.f), (float)(1536 - 1));
    boxes[idx * 4 + 1] = fminf(fmaxf(p1, 0.f), (float)(1536 - 1));
    boxes[idx * 4 + 2] = fminf(fmaxf(p2, 0.f), (float)(1536 - 1));
    boxes[idx * 4 + 3] = fminf(fmaxf(p3, 0.f), (float)(1536 - 1));
    cls2[idx * 2 + 0] = c0; cls2[idx * 2 + 1] = c1;
    float d = c1 - c0;
    dval[idx] = d;
    atomicAdd(&hist[key_of(d) >> 16], 1u);
}

// ---------------------------------------------------------------------------
// threshold: find histogram bin T containing rank-6000 (ascending key = desc d)
// ---------------------------------------------------------------------------
__global__ void k_thresh(const unsigned int* __restrict__ hist, unsigned int* __restrict__ ctrl) {
    __shared__ unsigned int s[256];
    __shared__ unsigned int chunkIdx, baseCount;
    int t = threadIdx.x;
    unsigned int sum = 0;
    for (int i = 0; i < 256; ++i) sum += hist[t * 256 + i];
    s[t] = sum;
    __syncthreads();
    if (t == 0) {
        unsigned int cum = 0; int c = 0;
        for (; c < 256; ++c) { if (cum + s[c] >= TOPN) break; cum += s[c]; }
        chunkIdx = (unsigned int)c; baseCount = cum;
    }
    __syncthreads();
    unsigned int bin = hist[chunkIdx * 256 + t];
    s[t] = bin;
    __syncthreads();
    if (t == 0) {
        unsigned int cum = baseCount; int b = 0;
        for (; b < 256; ++b) { cum += s[b]; if (cum >= TOPN) break; }
        ctrl[1] = chunkIdx * 256 + (unsigned int)b;  // T
        ctrl[2] = cum;                               // count(bin <= T), info
    }
}

// ---------------------------------------------------------------------------
// compact candidates (bin <= T) as (key32<<32)|idx
// ---------------------------------------------------------------------------
__global__ void k_compact(const float* __restrict__ dval, unsigned int* __restrict__ ctrl,
                          unsigned long long* __restrict__ cand) {
    int idx = blockIdx.x * 256 + threadIdx.x;
    if (idx >= NA) return;
    unsigned int k2 = key_of(dval[idx]);
    if ((k2 >> 16) <= ctrl[1]) {
        unsigned int pos = atomicAdd(&ctrl[0], 1u);
        if (pos < CAND_CAP) cand[pos] = ((unsigned long long)k2 << 32) | (unsigned int)idx;
    }
}

// ---------------------------------------------------------------------------
// single-block bitonic sort of <=8192 candidates; emit top-6000 boxes+probs
// ---------------------------------------------------------------------------
__global__ __launch_bounds__(1024) void k_sort(const unsigned long long* __restrict__ cand,
                                               const unsigned int* __restrict__ ctrl,
                                               const float* __restrict__ boxes,
                                               const float* __restrict__ dval,
                                               float* __restrict__ topBoxes,
                                               float* __restrict__ topProbs) {
    __shared__ unsigned long long sk[CAND_CAP];   // 64 KB
    int t = threadIdx.x;
    unsigned int n = ctrl[0]; if (n > CAND_CAP) n = CAND_CAP;
    for (int i = t; i < CAND_CAP; i += 1024)
        sk[i] = (i < (int)n) ? cand[i] : 0xFFFFFFFFFFFFFFFFull;
    __syncthreads();
    for (int k = 2; k <= CAND_CAP; k <<= 1) {
        for (int j = k >> 1; j >= 1; j >>= 1) {
            for (int t2 = t; t2 < CAND_CAP / 2; t2 += 1024) {
                int i = ((t2 & ~(j - 1)) << 1) | (t2 & (j - 1));
                int ixj = i + j;
                unsigned long long a = sk[i], b = sk[ixj];
                bool up = ((i & k) == 0);
                if ((a > b) == up) { sk[i] = b; sk[ixj] = a; }
            }
            __syncthreads();
        }
    }
    for (int r = t; r < TOPN; r += 1024) {
        unsigned int idx = (unsigned int)sk[r];
        float4 b4 = ((const float4*)boxes)[idx];
        ((float4*)topBoxes)[r] = b4;
        topProbs[r] = 1.f / (1.f + expf(-dval[idx]));
    }
}

// ---------------------------------------------------------------------------
// NMS suppression bitmask: mask[i][c] bit b = (IoU(i, c*64+b) > 0.7 && j > i)
// ---------------------------------------------------------------------------
__global__ void k_mask(const float* __restrict__ topBoxes, unsigned long long* __restrict__ mask) {
    int g = blockIdx.x * 256 + threadIdx.x;
    if (g >= TOPN * NW) return;
    int i = g / NW, c = g - i * NW;
    if (c < (i >> 6)) return;                  // never read
    float x0i = topBoxes[i * 4 + 0], y0i = topBoxes[i * 4 + 1];
    float x1i = topBoxes[i * 4 + 2], y1i = topBoxes[i * 4 + 3];
    float ai = (x1i - x0i + 1.f) * (y1i - y0i + 1.f);
    unsigned long long m = 0;
    int j0 = c * 64;
    for (int b = 0; b < 64; ++b) {
        int j = j0 + b;
        if (j >= TOPN || j <= i) continue;
        float x0j = topBoxes[j * 4 + 0], y0j = topBoxes[j * 4 + 1];
        float x1j = topBoxes[j * 4 + 2], y1j = topBoxes[j * 4 + 3];
        float aj = (x1j - x0j + 1.f) * (y1j - y0j + 1.f);
        float iw = fmaxf(fminf(x1i, x1j) - fmaxf(x0i, x0j) + 1.f, 0.f);
        float ih = fmaxf(fminf(y1i, y1j) - fmaxf(y0i, y0j) + 1.f, 0.f);
        float inter = iw * ih;
        float iou = inter / (ai + aj - inter);
        if (iou > 0.7f) m |= (1ull << b);
    }
    mask[(size_t)i * NW + c] = m;
}

// ---------------------------------------------------------------------------
// greedy scan, single wave, chunk-parallel, early exit at 300 kept
// ---------------------------------------------------------------------------
__global__ __launch_bounds__(64) void k_scan(const unsigned long long* __restrict__ mask,
                                             const float* __restrict__ topBoxes,
                                             const float* __restrict__ topProbs,
                                             float* __restrict__ out2, float* __restrict__ out3) {
    __shared__ unsigned long long kw[NW];
    int l = threadIdx.x;
    for (int i = l; i < NW; i += 64)
        kw[i] = (i == NW - 1) ? 0x0000FFFFFFFFFFFFull : ~0ull;  // 6000 = 93*64+48
    __syncthreads();
    int kept = 0;
    for (int c = 0; c < NW && kept < POSN; ++c) {
        unsigned long long w = kw[c];
        unsigned long long m = mask[(size_t)(c * 64 + l) * NW + c];
        for (int b = 0; b < 64; ++b) {
            if ((w >> b) & 1ull) {               // uniform branch
                unsigned long long mb = __shfl(m, b);
                w &= ~mb;
            }
        }
        if ((w >> l) & 1ull) {
            int r = kept + __popcll(w & ((1ull << l) - 1ull));
            if (r < POSN) {
                int j = c * 64 + l;
                out2[r * 4 + 0] = topBoxes[j * 4 + 0];
                out2[r * 4 + 1] = topBoxes[j * 4 + 1];
                out2[r * 4 + 2] = topBoxes[j * 4 + 2];
                out2[r * 4 + 3] = topBoxes[j * 4 + 3];
                out3[r] = topProbs[j];
            }
        }
        kept += __popcll(w);
        if (kept >= POSN) break;
        for (int c2 = c + 1 + l; c2 < NW; c2 += 64) {
            unsigned long long sup = 0;
            for (int b = 0; b < 64; ++b)
                if ((w >> b) & 1ull) sup |= mask[(size_t)(c * 64 + b) * NW + c2];
            kw[c2] &= ~sup;
        }
        __syncthreads();
    }
    for (int r = kept + l; r < POSN; r += 64) {
        out2[r * 4 + 0] = 0.f; out2[r * 4 + 1] = 0.f;
        out2[r * 4 + 2] = 0.f; out2[r * 4 + 3] = 0.f;
        out3[r] = 0.f;
    }
}

// ---------------------------------------------------------------------------
// gather proposals/cls at valid_idx
// ---------------------------------------------------------------------------
__global__ void k_gather(const int* __restrict__ vidx, const float* __restrict__ props,
                         const float* __restrict__ cls2, float* __restrict__ out0,
                         float* __restrict__ out1, int nv) {
    int i = blockIdx.x * 256 + threadIdx.x;
    if (i >= nv) return;
    int v = vidx[i];
    ((float4*)out0)[i] = ((const float4*)props)[v];
    ((float2*)out1)[i] = ((const float2*)cls2)[v];
}

// ---------------------------------------------------------------------------
extern "C" void kernel_launch(void* const* d_in, const int* in_sizes, int n_in,
                              void* d_out, int out_size, void* d_ws, size_t ws_size,
                              hipStream_t stream) {
    const float* x       = (const float*)d_in[0];
    const float* w_rpn   = (const float*)d_in[1];
    const float* b_rpn   = (const float*)d_in[2];
    const float* w_cls   = (const float*)d_in[3];
    const float* b_cls   = (const float*)d_in[4];
    const float* w_reg   = (const float*)d_in[5];
    const float* b_reg   = (const float*)d_in[6];
    const float* anchors = (const float*)d_in[7];
    const int*   vidx    = (const int*)d_in[8];
    const int nv = in_sizes[8];

    char* ws = (char*)d_ws;
    float* accum            = (float*)(ws + 0);        // 497664 f  (~2.0 MB)
    float* props            = (float*)(ws + 1990656);  // 82944*4 f
    float* boxes            = (float*)(ws + 3317760);  // 82944*4 f
    float* cls2             = (float*)(ws + 4644864);  // 82944*2 f
    float* dval             = (float*)(ws + 5308416);  // 82944 f
    unsigned int* hist      = (unsigned int*)(ws + 5640192);  // 65536 u32
    unsigned int* ctrl      = (unsigned int*)(ws + 5902336);  // 16 u32
    unsigned long long* cand = (unsigned long long*)(ws + 5902400); // 8192 u64
    float* topBoxes         = (float*)(ws + 6033472);  // 6000*4 f
    float* topProbs         = (float*)(ws + 6129472);  // 6000 f
    unsigned long long* mask = (unsigned long long*)(ws + 6153472); // 6000*94 u64 (~4.5MB)

    float* out0 = (float*)d_out;
    float* out1 = out0 + (size_t)nv * 4;
    float* out2 = out1 + (size_t)nv * 2;
    float* out3 = out2 + (size_t)POSN * 4;

    k_init<<<(NPIX * NCH + 65536 + 16 + 255) / 256, 256, 0, stream>>>(b_cls, b_reg, accum, hist, ctrl);
    k_conv<<<dim3(8, 96), 128, 0, stream>>>(x, w_rpn, b_rpn, w_cls, w_reg, accum);
    k_decode<<<(NA + 255) / 256, 256, 0, stream>>>(accum, anchors, props, boxes, cls2, dval, hist);
    k_thresh<<<1, 256, 0, stream>>>(hist, ctrl);
    k_compact<<<(NA + 255) / 256, 256, 0, stream>>>(dval, ctrl, cand);
    k_sort<<<1, 1024, 0, stream>>>(cand, ctrl, boxes, dval, topBoxes, topProbs);
    k_mask<<<(TOPN * NW + 255) / 256, 256, 0, stream>>>(topBoxes, mask);
    k_scan<<<1, 64, 0, stream>>>(mask, topBoxes, topProbs, out2, out3);
    k_gather<<<(nv + 255) / 256, 256, 0, stream>>>(vidx, props, cls2, out0, out1, nv);
}

// Round 2
// 2122.355 us; speedup vs baseline: 2.4588x; 2.4588x over previous
//
#include <hip/hip_runtime.h>

#define H 96
#define W 96
#define CIN 1024
#define NPIX 9216          // 96*96
#define NCH 54             // 18 cls + 36 reg channels
#define NA 82944           // 9216*9 anchors
#define TOPN 6000
#define NW 94              // ceil(6000/64)
#define POSN 300
#define CAND_CAP 8192

// ---------------------------------------------------------------------------
// init: accum <- bias (conv partials added atomically later), hist/ctrl <- 0
// ---------------------------------------------------------------------------
__global__ void k_init(const float* __restrict__ b_cls, const float* __restrict__ b_reg,
                       float* __restrict__ accum, unsigned int* __restrict__ hist,
                       unsigned int* __restrict__ ctrl) {
    int t = blockIdx.x * 256 + threadIdx.x;
    if (t < NPIX * NCH) {
        int ch = t % NCH;
        accum[t] = (ch < 18) ? b_cls[ch] : b_reg[ch - 18];
    } else if (t < NPIX * NCH + 65536) {
        hist[t - NPIX * NCH] = 0u;
    } else if (t < NPIX * NCH + 65536 + 16) {
        ctrl[t - NPIX * NCH - 65536] = 0u;
    }
}

// ---------------------------------------------------------------------------
// weight transpose: wr[512co][1024ci][9k] -> wt[(cb*9216 + ci*9+k)*64 + co]
// LDS-tiled so both global read and write are coalesced.
// grid (8 cb, 128 cc), 256 threads; tile = 64co x 72(ci*9+k within chunk)
// ---------------------------------------------------------------------------
__global__ __launch_bounds__(256) void k_wtr(const float* __restrict__ wr,
                                             float* __restrict__ wt) {
    __shared__ float tile[64 * 73];
    const int tid = threadIdx.x;
    const int cb = blockIdx.x;   // 0..7
    const int cc = blockIdx.y;   // 0..127
    // phase 1: coalesced-ish read (72-float runs per co), conflict-free LDS write
    for (int i = tid; i < 4608; i += 256) {
        int co = i / 72, j = i - co * 72;
        tile[co * 73 + j] = wr[(size_t)(cb * 64 + co) * 9216 + cc * 72 + j];
    }
    __syncthreads();
    // phase 2: conflict-free LDS read (73*co -> distinct banks), coalesced write
    float* out = wt + ((size_t)cb * 9216 + cc * 72) * 64;
    for (int o = tid; o < 4608; o += 256) {
        int j = o >> 6, co = o & 63;
        out[o] = tile[co * 73 + j];
    }
}

// ---------------------------------------------------------------------------
// fused conv3x3(1024->512)+bias+relu + conv1x1 partials (54 ch) -> atomicAdd
// grid (8 co-blocks, 96 rows), 256 threads. thread = 2 co x 12 px.
//   pxg = tid & 7  (8 groups of 12 px), cog = tid >> 3 (32 groups of 2 co)
// LDS: xs [8ci][3ky][100] (pad left/right, 16B-aligned rows)
//      wc [72 = ci*9+k][64 co]   (weight reads are float2 broadcast)
// ---------------------------------------------------------------------------
__global__ __launch_bounds__(256, 4) void k_conv(const float* __restrict__ x,
                                                 const float* __restrict__ wt,
                                                 const float* __restrict__ br,
                                                 const float* __restrict__ wcl,
                                                 const float* __restrict__ wrg,
                                                 float* __restrict__ accum) {
    __shared__ __align__(16) float lds[9728];
    const int tid = threadIdx.x;
    const int cb = blockIdx.x;   // co block: 64 channels
    const int y  = blockIdx.y;   // output row
    const int pxg = tid & 7;     // 8 px-groups of 12
    const int cog = tid >> 3;    // 32 co-groups of 2
    const int x0 = pxg * 12;

    float acc[2][12];
#pragma unroll
    for (int c = 0; c < 2; ++c)
#pragma unroll
        for (int i = 0; i < 12; ++i) acc[c][i] = 0.f;

    float* xs = lds;           // 24 rows x 100 (row[0]=x[-1], row[97]=x[96], zeros)
    float* wc = lds + 2400;    // 72 x 64

    // zero the pad columns once (cols 0,97,98,99 of each of 24 rows)
    for (int i = tid; i < 96; i += 256) {
        int row = i >> 2, p = i & 3;
        int col = (p == 0) ? 0 : (96 + p);
        xs[row * 100 + col] = 0.f;
    }
    __syncthreads();

    const float4* wsrc_base = (const float4*)(wt + (size_t)cb * 9216 * 64);

    for (int cc = 0; cc < CIN / 8; ++cc) {
        // ---- stage x: 8ci x 3rows x 96, coalesced scalar ----
        for (int i = tid; i < 2304; i += 256) {
            int ci = i / 288; int rem = i - ci * 288;
            int r = rem / 96; int xx = rem - r * 96;
            int yy = y + r - 1;
            float v = 0.f;
            if (yy >= 0 && yy < H) v = x[(size_t)(cc * 8 + ci) * NPIX + yy * W + xx];
            xs[(ci * 3 + r) * 100 + xx + 1] = v;
        }
        // ---- stage w: 4608 floats contiguous (transposed layout) ----
        {
            const float4* wsrc = wsrc_base + (size_t)cc * 72 * 16;  // 72*64/4
            float4* wdst = (float4*)wc;
            for (int i = tid; i < 1152; i += 256) wdst[i] = wsrc[i];
        }
        __syncthreads();

        for (int ci = 0; ci < 8; ++ci) {
#pragma unroll
            for (int ky = 0; ky < 3; ++ky) {
                const float* xrow = &xs[(ci * 3 + ky) * 100 + x0];
                float4 a = ((const float4*)xrow)[0];
                float4 b = ((const float4*)xrow)[1];
                float4 c = ((const float4*)xrow)[2];
                float2 d = *(const float2*)(xrow + 12);
                float xv[14] = {a.x, a.y, a.z, a.w, b.x, b.y, b.z, b.w,
                                c.x, c.y, c.z, c.w, d.x, d.y};
                const float* wrow = &wc[(ci * 9 + ky * 3) * 64 + cog * 2];
                float2 w0 = *(const float2*)(wrow);
                float2 w1 = *(const float2*)(wrow + 64);
                float2 w2 = *(const float2*)(wrow + 128);
#pragma unroll
                for (int p = 0; p < 12; ++p) {
                    acc[0][p] += w0.x * xv[p] + w1.x * xv[p + 1] + w2.x * xv[p + 2];
                    acc[1][p] += w0.y * xv[p] + w1.y * xv[p + 1] + w2.y * xv[p + 2];
                }
            }
        }
        __syncthreads();
    }

    // ---- epilogue: relu(h) tile -> LDS, 1x1 conv partials -> atomicAdd ----
    float* hs  = lds;         // [64][97] (+1 pad)
    float* wcs = lds + 6208;  // [54][65]
#pragma unroll
    for (int c = 0; c < 2; ++c) {
        float b = br[cb * 64 + cog * 2 + c];
#pragma unroll
        for (int p = 0; p < 12; ++p)
            hs[(cog * 2 + c) * 97 + x0 + p] = fmaxf(acc[c][p] + b, 0.f);
    }
    for (int i = tid; i < NCH * 64; i += 256) {
        int ch = i >> 6, co = i & 63;
        float v = (ch < 18) ? wcl[ch * 512 + cb * 64 + co]
                            : wrg[(ch - 18) * 512 + cb * 64 + co];
        wcs[ch * 65 + co] = v;
    }
    __syncthreads();
    for (int i = tid; i < 96 * NCH; i += 256) {
        int px = i / NCH, ch = i - px * NCH;
        float s = 0.f;
#pragma unroll 4
        for (int co = 0; co < 64; ++co) s += hs[co * 97 + px] * wcs[ch * 65 + co];
        atomicAdd(&accum[(y * 96 + px) * NCH + ch], s);
    }
}

// ---------------------------------------------------------------------------
// decode: anchors + reg -> proposals/clipped boxes; cls -> d = c1-c0; histogram
// ---------------------------------------------------------------------------
__device__ __forceinline__ unsigned int key_of(float d) {
    unsigned int u = __float_as_uint(d);
    unsigned int k = (u & 0x80000000u) ? ~u : (u | 0x80000000u);  // asc in d
    return ~k;                                                     // asc key = desc d
}

__global__ void k_decode(const float* __restrict__ accum, const float* __restrict__ anchors,
                         float* __restrict__ props, float* __restrict__ boxes,
                         float* __restrict__ cls2, float* __restrict__ dval,
                         unsigned int* __restrict__ hist) {
    int idx = blockIdx.x * 256 + threadIdx.x;
    if (idx >= NA) return;
    int p = idx / 9, a = idx - p * 9;
    const float* ac = accum + p * NCH;
    float c0 = ac[2 * a], c1 = ac[2 * a + 1];
    float r0 = ac[18 + 4 * a + 0], r1 = ac[18 + 4 * a + 1];
    float r2 = ac[18 + 4 * a + 2], r3 = ac[18 + 4 * a + 3];
    const float* A = anchors + (size_t)idx * 4;
    float aw = A[2] - A[0] + 1.f, ah = A[3] - A[1] + 1.f;
    float ax = A[0] + 0.5f * (aw - 1.f), ay = A[1] + 0.5f * (ah - 1.f);
    float px = ax + aw * r0, py = ay + ah * r1;
    float pw = aw * expf(r2), ph = ah * expf(r3);
    float p0 = px - 0.5f * (pw - 1.f), p1 = py - 0.5f * (ph - 1.f);
    float p2 = px + 0.5f * (pw - 1.f), p3 = py + 0.5f * (ph - 1.f);
    props[idx * 4 + 0] = p0; props[idx * 4 + 1] = p1;
    props[idx * 4 + 2] = p2; props[idx * 4 + 3] = p3;
    boxes[idx * 4 + 0] = fminf(fmaxf(p0, 0.f), (float)(1536 - 1));
    boxes[idx * 4 + 1] = fminf(fmaxf(p1, 0.f), (float)(1536 - 1));
    boxes[idx * 4 + 2] = fminf(fmaxf(p2, 0.f), (float)(1536 - 1));
    boxes[idx * 4 + 3] = fminf(fmaxf(p3, 0.f), (float)(1536 - 1));
    cls2[idx * 2 + 0] = c0; cls2[idx * 2 + 1] = c1;
    float d = c1 - c0;
    dval[idx] = d;
    atomicAdd(&hist[key_of(d) >> 16], 1u);
}

// ---------------------------------------------------------------------------
// threshold: find histogram bin T containing rank-6000 (ascending key = desc d)
// ---------------------------------------------------------------------------
__global__ void k_thresh(const unsigned int* __restrict__ hist, unsigned int* __restrict__ ctrl) {
    __shared__ unsigned int s[256];
    __shared__ unsigned int chunkIdx, baseCount;
    int t = threadIdx.x;
    unsigned int sum = 0;
    for (int i = 0; i < 256; ++i) sum += hist[t * 256 + i];
    s[t] = sum;
    __syncthreads();
    if (t == 0) {
        unsigned int cum = 0; int c = 0;
        for (; c < 256; ++c) { if (cum + s[c] >= TOPN) break; cum += s[c]; }
        chunkIdx = (unsigned int)c; baseCount = cum;
    }
    __syncthreads();
    unsigned int bin = hist[chunkIdx * 256 + t];
    s[t] = bin;
    __syncthreads();
    if (t == 0) {
        unsigned int cum = baseCount; int b = 0;
        for (; b < 256; ++b) { cum += s[b]; if (cum >= TOPN) break; }
        ctrl[1] = chunkIdx * 256 + (unsigned int)b;  // T
        ctrl[2] = cum;                               // count(bin <= T), info
    }
}

// ---------------------------------------------------------------------------
// compact candidates (bin <= T) as (key32<<32)|idx
// ---------------------------------------------------------------------------
__global__ void k_compact(const float* __restrict__ dval, unsigned int* __restrict__ ctrl,
                          unsigned long long* __restrict__ cand) {
    int idx = blockIdx.x * 256 + threadIdx.x;
    if (idx >= NA) return;
    unsigned int k2 = key_of(dval[idx]);
    if ((k2 >> 16) <= ctrl[1]) {
        unsigned int pos = atomicAdd(&ctrl[0], 1u);
        if (pos < CAND_CAP) cand[pos] = ((unsigned long long)k2 << 32) | (unsigned int)idx;
    }
}

// ---------------------------------------------------------------------------
// single-block bitonic sort of <=8192 candidates; emit top-6000 boxes+probs
// ---------------------------------------------------------------------------
__global__ __launch_bounds__(1024) void k_sort(const unsigned long long* __restrict__ cand,
                                               const unsigned int* __restrict__ ctrl,
                                               const float* __restrict__ boxes,
                                               const float* __restrict__ dval,
                                               float* __restrict__ topBoxes,
                                               float* __restrict__ topProbs) {
    __shared__ unsigned long long sk[CAND_CAP];   // 64 KB
    int t = threadIdx.x;
    unsigned int n = ctrl[0]; if (n > CAND_CAP) n = CAND_CAP;
    for (int i = t; i < CAND_CAP; i += 1024)
        sk[i] = (i < (int)n) ? cand[i] : 0xFFFFFFFFFFFFFFFFull;
    __syncthreads();
    for (int k = 2; k <= CAND_CAP; k <<= 1) {
        for (int j = k >> 1; j >= 1; j >>= 1) {
            for (int t2 = t; t2 < CAND_CAP / 2; t2 += 1024) {
                int i = ((t2 & ~(j - 1)) << 1) | (t2 & (j - 1));
                int ixj = i + j;
                unsigned long long a = sk[i], b = sk[ixj];
                bool up = ((i & k) == 0);
                if ((a > b) == up) { sk[i] = b; sk[ixj] = a; }
            }
            __syncthreads();
        }
    }
    for (int r = t; r < TOPN; r += 1024) {
        unsigned int idx = (unsigned int)sk[r];
        float4 b4 = ((const float4*)boxes)[idx];
        ((float4*)topBoxes)[r] = b4;
        topProbs[r] = 1.f / (1.f + expf(-dval[idx]));
    }
}

// ---------------------------------------------------------------------------
// NMS suppression bitmask: mask[i][c] bit b = (IoU(i, c*64+b) > 0.7 && j > i)
// ---------------------------------------------------------------------------
__global__ void k_mask(const float* __restrict__ topBoxes, unsigned long long* __restrict__ mask) {
    int g = blockIdx.x * 256 + threadIdx.x;
    if (g >= TOPN * NW) return;
    int i = g / NW, c = g - i * NW;
    if (c < (i >> 6)) return;                  // never read
    float x0i = topBoxes[i * 4 + 0], y0i = topBoxes[i * 4 + 1];
    float x1i = topBoxes[i * 4 + 2], y1i = topBoxes[i * 4 + 3];
    float ai = (x1i - x0i + 1.f) * (y1i - y0i + 1.f);
    unsigned long long m = 0;
    int j0 = c * 64;
    for (int b = 0; b < 64; ++b) {
        int j = j0 + b;
        if (j >= TOPN || j <= i) continue;
        float x0j = topBoxes[j * 4 + 0], y0j = topBoxes[j * 4 + 1];
        float x1j = topBoxes[j * 4 + 2], y1j = topBoxes[j * 4 + 3];
        float aj = (x1j - x0j + 1.f) * (y1j - y0j + 1.f);
        float iw = fmaxf(fminf(x1i, x1j) - fmaxf(x0i, x0j) + 1.f, 0.f);
        float ih = fmaxf(fminf(y1i, y1j) - fmaxf(y0i, y0j) + 1.f, 0.f);
        float inter = iw * ih;
        float iou = inter / (ai + aj - inter);
        if (iou > 0.7f) m |= (1ull << b);
    }
    mask[(size_t)i * NW + c] = m;
}

// ---------------------------------------------------------------------------
// greedy scan, single wave, chunk-parallel, early exit at 300 kept
// ---------------------------------------------------------------------------
__global__ __launch_bounds__(64) void k_scan(const unsigned long long* __restrict__ mask,
                                             const float* __restrict__ topBoxes,
                                             const float* __restrict__ topProbs,
                                             float* __restrict__ out2, float* __restrict__ out3) {
    __shared__ unsigned long long kw[NW];
    int l = threadIdx.x;
    for (int i = l; i < NW; i += 64)
        kw[i] = (i == NW - 1) ? 0x0000FFFFFFFFFFFFull : ~0ull;  // 6000 = 93*64+48
    __syncthreads();
    int kept = 0;
    for (int c = 0; c < NW && kept < POSN; ++c) {
        unsigned long long w = kw[c];
        unsigned long long m = mask[(size_t)(c * 64 + l) * NW + c];
        for (int b = 0; b < 64; ++b) {
            if ((w >> b) & 1ull) {               // uniform branch
                unsigned long long mb = __shfl(m, b);
                w &= ~mb;
            }
        }
        if ((w >> l) & 1ull) {
            int r = kept + __popcll(w & ((1ull << l) - 1ull));
            if (r < POSN) {
                int j = c * 64 + l;
                out2[r * 4 + 0] = topBoxes[j * 4 + 0];
                out2[r * 4 + 1] = topBoxes[j * 4 + 1];
                out2[r * 4 + 2] = topBoxes[j * 4 + 2];
                out2[r * 4 + 3] = topBoxes[j * 4 + 3];
                out3[r] = topProbs[j];
            }
        }
        kept += __popcll(w);
        if (kept >= POSN) break;
        for (int c2 = c + 1 + l; c2 < NW; c2 += 64) {
            unsigned long long sup = 0;
            for (int b = 0; b < 64; ++b)
                if ((w >> b) & 1ull) sup |= mask[(size_t)(c * 64 + b) * NW + c2];
            kw[c2] &= ~sup;
        }
        __syncthreads();
    }
    for (int r = kept + l; r < POSN; r += 64) {
        out2[r * 4 + 0] = 0.f; out2[r * 4 + 1] = 0.f;
        out2[r * 4 + 2] = 0.f; out2[r * 4 + 3] = 0.f;
        out3[r] = 0.f;
    }
}

// ---------------------------------------------------------------------------
// gather proposals/cls at valid_idx
// ---------------------------------------------------------------------------
__global__ void k_gather(const int* __restrict__ vidx, const float* __restrict__ props,
                         const float* __restrict__ cls2, float* __restrict__ out0,
                         float* __restrict__ out1, int nv) {
    int i = blockIdx.x * 256 + threadIdx.x;
    if (i >= nv) return;
    int v = vidx[i];
    ((float4*)out0)[i] = ((const float4*)props)[v];
    ((float2*)out1)[i] = ((const float2*)cls2)[v];
}

// ---------------------------------------------------------------------------
extern "C" void kernel_launch(void* const* d_in, const int* in_sizes, int n_in,
                              void* d_out, int out_size, void* d_ws, size_t ws_size,
                              hipStream_t stream) {
    const float* x       = (const float*)d_in[0];
    const float* w_rpn   = (const float*)d_in[1];
    const float* b_rpn   = (const float*)d_in[2];
    const float* w_cls   = (const float*)d_in[3];
    const float* b_cls   = (const float*)d_in[4];
    const float* w_reg   = (const float*)d_in[5];
    const float* b_reg   = (const float*)d_in[6];
    const float* anchors = (const float*)d_in[7];
    const int*   vidx    = (const int*)d_in[8];
    const int nv = in_sizes[8];

    char* ws = (char*)d_ws;
    float* accum            = (float*)(ws + 0);        // 497664 f  (~2.0 MB)
    float* props            = (float*)(ws + 1990656);  // 82944*4 f
    float* boxes            = (float*)(ws + 3317760);  // 82944*4 f
    float* cls2             = (float*)(ws + 4644864);  // 82944*2 f
    float* dval             = (float*)(ws + 5308416);  // 82944 f
    unsigned int* hist      = (unsigned int*)(ws + 5640192);  // 65536 u32
    unsigned int* ctrl      = (unsigned int*)(ws + 5902336);  // 16 u32
    unsigned long long* cand = (unsigned long long*)(ws + 5902400); // 8192 u64
    float* topBoxes         = (float*)(ws + 6033472);  // 6000*4 f
    float* topProbs         = (float*)(ws + 6129472);  // 6000 f
    unsigned long long* mask = (unsigned long long*)(ws + 6153472); // 6000*94 u64 (~4.5MB)
    float* wt               = (float*)(ws + 10665472); // 512*9216 f (18.9 MB) transposed weights

    float* out0 = (float*)d_out;
    float* out1 = out0 + (size_t)nv * 4;
    float* out2 = out1 + (size_t)nv * 2;
    float* out3 = out2 + (size_t)POSN * 4;

    k_init<<<(NPIX * NCH + 65536 + 16 + 255) / 256, 256, 0, stream>>>(b_cls, b_reg, accum, hist, ctrl);
    k_wtr<<<dim3(8, 128), 256, 0, stream>>>(w_rpn, wt);
    k_conv<<<dim3(8, 96), 256, 0, stream>>>(x, wt, b_rpn, w_cls, w_reg, accum);
    k_decode<<<(NA + 255) / 256, 256, 0, stream>>>(accum, anchors, props, boxes, cls2, dval, hist);
    k_thresh<<<1, 256, 0, stream>>>(hist, ctrl);
    k_compact<<<(NA + 255) / 256, 256, 0, stream>>>(dval, ctrl, cand);
    k_sort<<<1, 1024, 0, stream>>>(cand, ctrl, boxes, dval, topBoxes, topProbs);
    k_mask<<<(TOPN * NW + 255) / 256, 256, 0, stream>>>(topBoxes, mask);
    k_scan<<<1, 64, 0, stream>>>(mask, topBoxes, topProbs, out2, out3);
    k_gather<<<(nv + 255) / 256, 256, 0, stream>>>(vidx, props, cls2, out0, out1, nv);
}

// Round 3
// 1284.014 us; speedup vs baseline: 4.0641x; 1.6529x over previous
//
#include <hip/hip_runtime.h>

#define H 96
#define W 96
#define CIN 1024
#define NPIX 9216          // 96*96
#define NCH 54             // 18 cls + 36 reg channels
#define NA 82944           // 9216*9 anchors
#define TOPN 6000
#define NW 94              // ceil(6000/64)
#define POSN 300
#define CAND_CAP 8192

typedef _Float16 half8_t __attribute__((ext_vector_type(8)));
typedef float f32x4 __attribute__((ext_vector_type(4)));

#define CIP 40             // padded ci stride in halves (80 B = uniform 2-way banks, free)
#define XS_PLANE 11760     // 3*98*40 halves
#define WB_PLANE 5120      // 128*40 halves

// ---------------------------------------------------------------------------
// init: accum <- bias (conv partials added atomically later), hist/ctrl <- 0
// ---------------------------------------------------------------------------
__global__ void k_init(const float* __restrict__ b_cls, const float* __restrict__ b_reg,
                       float* __restrict__ accum, unsigned int* __restrict__ hist,
                       unsigned int* __restrict__ ctrl) {
    int t = blockIdx.x * 256 + threadIdx.x;
    if (t < NPIX * NCH) {
        int ch = t % NCH;
        accum[t] = (ch < 18) ? b_cls[ch] : b_reg[ch - 18];
    } else if (t < NPIX * NCH + 65536) {
        hist[t - NPIX * NCH] = 0u;
    } else if (t < NPIX * NCH + 65536 + 16) {
        ctrl[t - NPIX * NCH - 65536] = 0u;
    }
}

// ---------------------------------------------------------------------------
// x transpose + fp16 split: x[ci][px] fp32 -> xt_h[px][ci], xt_l[px][ci]
// lo plane scaled by 2048 to stay fp16-normal.
// grid (144 px-tiles, 16 ci-tiles), 256 thr, 64x64 tile via LDS
// ---------------------------------------------------------------------------
__global__ __launch_bounds__(256) void k_xtr(const float* __restrict__ x,
                                             _Float16* __restrict__ xh,
                                             _Float16* __restrict__ xl) {
    __shared__ float t[64 * 65];
    const int tid = threadIdx.x;
    const int px0 = blockIdx.x * 64, ci0 = blockIdx.y * 64;
    for (int i = tid; i < 4096; i += 256) {
        int ci = i >> 6, px = i & 63;
        t[ci * 65 + px] = x[(size_t)(ci0 + ci) * NPIX + px0 + px];
    }
    __syncthreads();
    for (int i = tid; i < 4096; i += 256) {
        int px = i >> 6, ci = i & 63;
        float v = t[ci * 65 + px];
        _Float16 h = (_Float16)v;
        size_t o = (size_t)(px0 + px) * 1024 + ci0 + ci;
        xh[o] = h;
        xl[o] = (_Float16)((v - (float)h) * 2048.f);
    }
}

// ---------------------------------------------------------------------------
// weight transform + fp16 split: wr[co][ci][9] -> wt[tap][co][ci] hi/lo
// thread per (co,ci): 9 contiguous reads, coalesced ci-contiguous writes.
// ---------------------------------------------------------------------------
__global__ __launch_bounds__(256) void k_wtr(const float* __restrict__ wr,
                                             _Float16* __restrict__ wh,
                                             _Float16* __restrict__ wl) {
    int t = blockIdx.x * 256 + threadIdx.x;   // < 524288
    int co = t >> 10, ci = t & 1023;
    const float* s = wr + ((size_t)co * 1024 + ci) * 9;
#pragma unroll
    for (int k = 0; k < 9; ++k) {
        float v = s[k];
        _Float16 h = (_Float16)v;
        size_t o = ((size_t)(k * 512) + co) * 1024 + ci;
        wh[o] = h;
        wl[o] = (_Float16)((v - (float)h) * 2048.f);
    }
}

// ---------------------------------------------------------------------------
// MFMA implicit-GEMM conv3x3(1024->512)+bias+relu + fused 1x1 partials.
// fp16 2-plane split: acc = Ah*Bh + (Ah*Bl' + Al'*Bh)/2048 (lo planes x2048).
// Block = 1 row (96 px) x 128 co, 4 waves; wave = 6 m-tiles x 2 n-tiles.
// grid (4 co-blocks, 96 rows), 256 thr.
// ---------------------------------------------------------------------------
__global__ __launch_bounds__(256, 2) void k_conv(
    const _Float16* __restrict__ xth, const _Float16* __restrict__ xtl,
    const _Float16* __restrict__ wth, const _Float16* __restrict__ wtl,
    const float* __restrict__ br, const float* __restrict__ wcl,
    const float* __restrict__ wrg, float* __restrict__ accum) {
    __shared__ __align__(16) char smem[77280];
    _Float16* xs = (_Float16*)smem;              // [2 pl][3 r][98 pxp][40]
    _Float16* wb = (_Float16*)(smem + 47040);    // [2 pl][128 co][40]

    const int tid = threadIdx.x;
    const int cb = blockIdx.x;        // co block of 128
    const int y  = blockIdx.y;        // output row
    const int l  = tid & 63;
    const int wv = tid >> 6;          // 0..3
    const int n0 = wv * 32;
    const int lm = l & 15;
    const int lk = l >> 4;            // 0..3

    f32x4 acc_h[6][2];
    f32x4 acc_x[6][2];
#pragma unroll
    for (int m2 = 0; m2 < 6; ++m2)
#pragma unroll
        for (int nt = 0; nt < 2; ++nt) {
            acc_h[m2][nt] = (f32x4){0.f, 0.f, 0.f, 0.f};
            acc_x[m2][nt] = (f32x4){0.f, 0.f, 0.f, 0.f};
        }

    // zero px pad columns (pxp = 0 and 97), both planes, 3 rows
    for (int i = tid; i < 480; i += 256) {
        int pl = i / 240, j = i - pl * 240;
        int r = j / 80, j2 = j - r * 80;
        int side = j2 / 40, c = j2 - side * 40;
        xs[pl * XS_PLANE + (r * 98 + side * 97) * CIP + c] = (_Float16)0.f;
    }

    for (int cc = 0; cc < 32; ++cc) {
        const int ci0 = cc * 32;
        __syncthreads();   // everyone done reading xs/wb of previous chunk

        // ---- stage x strip: 2 planes x 3 rows x 96 px x 32 ci ----
        for (int it = tid; it < 2304; it += 256) {
            int pl = (it >= 1152) ? 1 : 0;
            int j = it - pl * 1152;
            int r = j / 384; int j2 = j - r * 384;
            int px = j2 >> 2, q = j2 & 3;
            int yy = y + r - 1;
            float4 v = {0.f, 0.f, 0.f, 0.f};
            if (yy >= 0 && yy < H)
                v = *(const float4*)((pl ? xtl : xth) + (size_t)(yy * 96 + px) * 1024 + ci0 + q * 8);
            *(float4*)(xs + pl * XS_PLANE + (r * 98 + px + 1) * CIP + q * 8) = v;
        }

        // ---- prefetch tap-0 weights into regs ----
        float4 wreg[4];
#pragma unroll
        for (int k = 0; k < 4; ++k) {
            int item = k * 256 + tid;
            int pl = item >> 9, rem = item & 511;
            int co = rem >> 2, q = rem & 3;
            wreg[k] = *(const float4*)((pl ? wtl : wth) +
                        ((size_t)(cb * 128 + co)) * 1024 + ci0 + q * 8);
        }
        __syncthreads();   // xs visible
#pragma unroll
        for (int k = 0; k < 4; ++k) {
            int item = k * 256 + tid;
            int pl = item >> 9, rem = item & 511;
            int co = rem >> 2, q = rem & 3;
            *(float4*)(wb + pl * WB_PLANE + co * CIP + q * 8) = wreg[k];
        }
        __syncthreads();   // wb visible

        for (int tap = 0; tap < 9; ++tap) {
            if (tap < 8) {
#pragma unroll
                for (int k = 0; k < 4; ++k) {
                    int item = k * 256 + tid;
                    int pl = item >> 9, rem = item & 511;
                    int co = rem >> 2, q = rem & 3;
                    wreg[k] = *(const float4*)((pl ? wtl : wth) +
                                ((size_t)((tap + 1) * 512 + cb * 128 + co)) * 1024 + ci0 + q * 8);
                }
            }
            const int ky = tap / 3, kx = tap - 3 * (tap / 3);
            half8_t ah[6], al[6], bh[2], bl[2];
#pragma unroll
            for (int m2 = 0; m2 < 6; ++m2) {
                const int pxp = m2 * 16 + lm + kx;
                ah[m2] = *(const half8_t*)(xs + (ky * 98 + pxp) * CIP + lk * 8);
                al[m2] = *(const half8_t*)(xs + XS_PLANE + (ky * 98 + pxp) * CIP + lk * 8);
            }
#pragma unroll
            for (int nt = 0; nt < 2; ++nt) {
                bh[nt] = *(const half8_t*)(wb + (n0 + nt * 16 + lm) * CIP + lk * 8);
                bl[nt] = *(const half8_t*)(wb + WB_PLANE + (n0 + nt * 16 + lm) * CIP + lk * 8);
            }
#pragma unroll
            for (int m2 = 0; m2 < 6; ++m2)
#pragma unroll
                for (int nt = 0; nt < 2; ++nt)
                    acc_h[m2][nt] = __builtin_amdgcn_mfma_f32_16x16x32_f16(ah[m2], bh[nt], acc_h[m2][nt], 0, 0, 0);
#pragma unroll
            for (int m2 = 0; m2 < 6; ++m2)
#pragma unroll
                for (int nt = 0; nt < 2; ++nt)
                    acc_x[m2][nt] = __builtin_amdgcn_mfma_f32_16x16x32_f16(ah[m2], bl[nt], acc_x[m2][nt], 0, 0, 0);
#pragma unroll
            for (int m2 = 0; m2 < 6; ++m2)
#pragma unroll
                for (int nt = 0; nt < 2; ++nt)
                    acc_x[m2][nt] = __builtin_amdgcn_mfma_f32_16x16x32_f16(al[m2], bh[nt], acc_x[m2][nt], 0, 0, 0);
            if (tap < 8) {
                __syncthreads();   // all waves done reading wb
#pragma unroll
                for (int k = 0; k < 4; ++k) {
                    int item = k * 256 + tid;
                    int pl = item >> 9, rem = item & 511;
                    int co = rem >> 2, q = rem & 3;
                    *(float4*)(wb + pl * WB_PLANE + co * CIP + q * 8) = wreg[k];
                }
                __syncthreads();   // new wb visible
            }
        }
    }

    // ---- epilogue: h = relu(acc + bias) -> LDS, fp32 1x1 partials -> atomicAdd ----
    __syncthreads();
    float* hs  = (float*)smem;            // [96 px][128 co]
    float* wcs = (float*)(smem + 49152);  // [54 ch][130]
#pragma unroll
    for (int m2 = 0; m2 < 6; ++m2)
#pragma unroll
        for (int nt = 0; nt < 2; ++nt) {
            int co = n0 + nt * 16 + lm;
            float b = br[cb * 128 + co];
#pragma unroll
            for (int r = 0; r < 4; ++r) {
                int px = m2 * 16 + lk * 4 + r;
                float v = acc_h[m2][nt][r] + acc_x[m2][nt][r] * (1.f / 2048.f) + b;
                hs[px * 128 + co] = fmaxf(v, 0.f);
            }
        }
    for (int i = tid; i < NCH * 128; i += 256) {
        int ch = i >> 7, co = i & 127;
        wcs[ch * 130 + co] = (ch < 18) ? wcl[ch * 512 + cb * 128 + co]
                                       : wrg[(ch - 18) * 512 + cb * 128 + co];
    }
    __syncthreads();
    for (int i = tid; i < 96 * NCH; i += 256) {
        int px = i / NCH, ch = i - px * NCH;
        float s = 0.f;
#pragma unroll 8
        for (int co = 0; co < 128; ++co) s += hs[px * 128 + co] * wcs[ch * 130 + co];
        atomicAdd(&accum[(size_t)(y * 96 + px) * NCH + ch], s);
    }
}

// ---------------------------------------------------------------------------
// decode: anchors + reg -> proposals/clipped boxes; cls -> d = c1-c0; histogram
// ---------------------------------------------------------------------------
__device__ __forceinline__ unsigned int key_of(float d) {
    unsigned int u = __float_as_uint(d);
    unsigned int k = (u & 0x80000000u) ? ~u : (u | 0x80000000u);  // asc in d
    return ~k;                                                     // asc key = desc d
}

__global__ void k_decode(const float* __restrict__ accum, const float* __restrict__ anchors,
                         float* __restrict__ props, float* __restrict__ boxes,
                         float* __restrict__ cls2, float* __restrict__ dval,
                         unsigned int* __restrict__ hist) {
    int idx = blockIdx.x * 256 + threadIdx.x;
    if (idx >= NA) return;
    int p = idx / 9, a = idx - p * 9;
    const float* ac = accum + p * NCH;
    float c0 = ac[2 * a], c1 = ac[2 * a + 1];
    float r0 = ac[18 + 4 * a + 0], r1 = ac[18 + 4 * a + 1];
    float r2 = ac[18 + 4 * a + 2], r3 = ac[18 + 4 * a + 3];
    const float* A = anchors + (size_t)idx * 4;
    float aw = A[2] - A[0] + 1.f, ah = A[3] - A[1] + 1.f;
    float ax = A[0] + 0.5f * (aw - 1.f), ay = A[1] + 0.5f * (ah - 1.f);
    float px = ax + aw * r0, py = ay + ah * r1;
    float pw = aw * expf(r2), ph = ah * expf(r3);
    float p0 = px - 0.5f * (pw - 1.f), p1 = py - 0.5f * (ph - 1.f);
    float p2 = px + 0.5f * (pw - 1.f), p3 = py + 0.5f * (ph - 1.f);
    props[idx * 4 + 0] = p0; props[idx * 4 + 1] = p1;
    props[idx * 4 + 2] = p2; props[idx * 4 + 3] = p3;
    boxes[idx * 4 + 0] = fminf(fmaxf(p0, 0.f), (float)(1536 - 1));
    boxes[idx * 4 + 1] = fminf(fmaxf(p1, 0.f), (float)(1536 - 1));
    boxes[idx * 4 + 2] = fminf(fmaxf(p2, 0.f), (float)(1536 - 1));
    boxes[idx * 4 + 3] = fminf(fmaxf(p3, 0.f), (float)(1536 - 1));
    cls2[idx * 2 + 0] = c0; cls2[idx * 2 + 1] = c1;
    float d = c1 - c0;
    dval[idx] = d;
    atomicAdd(&hist[key_of(d) >> 16], 1u);
}

// ---------------------------------------------------------------------------
// threshold: find histogram bin T containing rank-6000 (ascending key = desc d)
// ---------------------------------------------------------------------------
__global__ void k_thresh(const unsigned int* __restrict__ hist, unsigned int* __restrict__ ctrl) {
    __shared__ unsigned int s[256];
    __shared__ unsigned int chunkIdx, baseCount;
    int t = threadIdx.x;
    unsigned int sum = 0;
    for (int i = 0; i < 256; ++i) sum += hist[t * 256 + i];
    s[t] = sum;
    __syncthreads();
    if (t == 0) {
        unsigned int cum = 0; int c = 0;
        for (; c < 256; ++c) { if (cum + s[c] >= TOPN) break; cum += s[c]; }
        chunkIdx = (unsigned int)c; baseCount = cum;
    }
    __syncthreads();
    unsigned int bin = hist[chunkIdx * 256 + t];
    s[t] = bin;
    __syncthreads();
    if (t == 0) {
        unsigned int cum = baseCount; int b = 0;
        for (; b < 256; ++b) { cum += s[b]; if (cum >= TOPN) break; }
        ctrl[1] = chunkIdx * 256 + (unsigned int)b;  // T
        ctrl[2] = cum;
    }
}

// ---------------------------------------------------------------------------
// compact candidates (bin <= T) as (key32<<32)|idx
// ---------------------------------------------------------------------------
__global__ void k_compact(const float* __restrict__ dval, unsigned int* __restrict__ ctrl,
                          unsigned long long* __restrict__ cand) {
    int idx = blockIdx.x * 256 + threadIdx.x;
    if (idx >= NA) return;
    unsigned int k2 = key_of(dval[idx]);
    if ((k2 >> 16) <= ctrl[1]) {
        unsigned int pos = atomicAdd(&ctrl[0], 1u);
        if (pos < CAND_CAP) cand[pos] = ((unsigned long long)k2 << 32) | (unsigned int)idx;
    }
}

// ---------------------------------------------------------------------------
// single-block bitonic sort of <=8192 candidates; emit top-6000 boxes+probs
// ---------------------------------------------------------------------------
__global__ __launch_bounds__(1024) void k_sort(const unsigned long long* __restrict__ cand,
                                               const unsigned int* __restrict__ ctrl,
                                               const float* __restrict__ boxes,
                                               const float* __restrict__ dval,
                                               float* __restrict__ topBoxes,
                                               float* __restrict__ topProbs) {
    __shared__ unsigned long long sk[CAND_CAP];   // 64 KB
    int t = threadIdx.x;
    unsigned int n = ctrl[0]; if (n > CAND_CAP) n = CAND_CAP;
    for (int i = t; i < CAND_CAP; i += 1024)
        sk[i] = (i < (int)n) ? cand[i] : 0xFFFFFFFFFFFFFFFFull;
    __syncthreads();
    for (int k = 2; k <= CAND_CAP; k <<= 1) {
        for (int j = k >> 1; j >= 1; j >>= 1) {
            for (int t2 = t; t2 < CAND_CAP / 2; t2 += 1024) {
                int i = ((t2 & ~(j - 1)) << 1) | (t2 & (j - 1));
                int ixj = i + j;
                unsigned long long a = sk[i], b = sk[ixj];
                bool up = ((i & k) == 0);
                if ((a > b) == up) { sk[i] = b; sk[ixj] = a; }
            }
            __syncthreads();
        }
    }
    for (int r = t; r < TOPN; r += 1024) {
        unsigned int idx = (unsigned int)sk[r];
        float4 b4 = ((const float4*)boxes)[idx];
        ((float4*)topBoxes)[r] = b4;
        topProbs[r] = 1.f / (1.f + expf(-dval[idx]));
    }
}

// ---------------------------------------------------------------------------
// NMS suppression bitmask
// ---------------------------------------------------------------------------
__global__ void k_mask(const float* __restrict__ topBoxes, unsigned long long* __restrict__ mask) {
    int g = blockIdx.x * 256 + threadIdx.x;
    if (g >= TOPN * NW) return;
    int i = g / NW, c = g - i * NW;
    if (c < (i >> 6)) return;
    float x0i = topBoxes[i * 4 + 0], y0i = topBoxes[i * 4 + 1];
    float x1i = topBoxes[i * 4 + 2], y1i = topBoxes[i * 4 + 3];
    float ai = (x1i - x0i + 1.f) * (y1i - y0i + 1.f);
    unsigned long long m = 0;
    int j0 = c * 64;
    for (int b = 0; b < 64; ++b) {
        int j = j0 + b;
        if (j >= TOPN || j <= i) continue;
        float x0j = topBoxes[j * 4 + 0], y0j = topBoxes[j * 4 + 1];
        float x1j = topBoxes[j * 4 + 2], y1j = topBoxes[j * 4 + 3];
        float aj = (x1j - x0j + 1.f) * (y1j - y0j + 1.f);
        float iw = fmaxf(fminf(x1i, x1j) - fmaxf(x0i, x0j) + 1.f, 0.f);
        float ih = fmaxf(fminf(y1i, y1j) - fmaxf(y0i, y0j) + 1.f, 0.f);
        float inter = iw * ih;
        float iou = inter / (ai + aj - inter);
        if (iou > 0.7f) m |= (1ull << b);
    }
    mask[(size_t)i * NW + c] = m;
}

// ---------------------------------------------------------------------------
// greedy scan, single wave, chunk-parallel, early exit at 300 kept
// ---------------------------------------------------------------------------
__global__ __launch_bounds__(64) void k_scan(const unsigned long long* __restrict__ mask,
                                             const float* __restrict__ topBoxes,
                                             const float* __restrict__ topProbs,
                                             float* __restrict__ out2, float* __restrict__ out3) {
    __shared__ unsigned long long kw[NW];
    int l = threadIdx.x;
    for (int i = l; i < NW; i += 64)
        kw[i] = (i == NW - 1) ? 0x0000FFFFFFFFFFFFull : ~0ull;  // 6000 = 93*64+48
    __syncthreads();
    int kept = 0;
    for (int c = 0; c < NW && kept < POSN; ++c) {
        unsigned long long w = kw[c];
        unsigned long long m = mask[(size_t)(c * 64 + l) * NW + c];
        for (int b = 0; b < 64; ++b) {
            if ((w >> b) & 1ull) {
                unsigned long long mb = __shfl(m, b);
                w &= ~mb;
            }
        }
        if ((w >> l) & 1ull) {
            int r = kept + __popcll(w & ((1ull << l) - 1ull));
            if (r < POSN) {
                int j = c * 64 + l;
                out2[r * 4 + 0] = topBoxes[j * 4 + 0];
                out2[r * 4 + 1] = topBoxes[j * 4 + 1];
                out2[r * 4 + 2] = topBoxes[j * 4 + 2];
                out2[r * 4 + 3] = topBoxes[j * 4 + 3];
                out3[r] = topProbs[j];
            }
        }
        kept += __popcll(w);
        if (kept >= POSN) break;
        for (int c2 = c + 1 + l; c2 < NW; c2 += 64) {
            unsigned long long sup = 0;
            for (int b = 0; b < 64; ++b)
                if ((w >> b) & 1ull) sup |= mask[(size_t)(c * 64 + b) * NW + c2];
            kw[c2] &= ~sup;
        }
        __syncthreads();
    }
    for (int r = kept + l; r < POSN; r += 64) {
        out2[r * 4 + 0] = 0.f; out2[r * 4 + 1] = 0.f;
        out2[r * 4 + 2] = 0.f; out2[r * 4 + 3] = 0.f;
        out3[r] = 0.f;
    }
}

// ---------------------------------------------------------------------------
// gather proposals/cls at valid_idx
// ---------------------------------------------------------------------------
__global__ void k_gather(const int* __restrict__ vidx, const float* __restrict__ props,
                         const float* __restrict__ cls2, float* __restrict__ out0,
                         float* __restrict__ out1, int nv) {
    int i = blockIdx.x * 256 + threadIdx.x;
    if (i >= nv) return;
    int v = vidx[i];
    ((float4*)out0)[i] = ((const float4*)props)[v];
    ((float2*)out1)[i] = ((const float2*)cls2)[v];
}

// ---------------------------------------------------------------------------
extern "C" void kernel_launch(void* const* d_in, const int* in_sizes, int n_in,
                              void* d_out, int out_size, void* d_ws, size_t ws_size,
                              hipStream_t stream) {
    const float* x       = (const float*)d_in[0];
    const float* w_rpn   = (const float*)d_in[1];
    const float* b_rpn   = (const float*)d_in[2];
    const float* w_cls   = (const float*)d_in[3];
    const float* b_cls   = (const float*)d_in[4];
    const float* w_reg   = (const float*)d_in[5];
    const float* b_reg   = (const float*)d_in[6];
    const float* anchors = (const float*)d_in[7];
    const int*   vidx    = (const int*)d_in[8];
    const int nv = in_sizes[8];

    char* ws = (char*)d_ws;
    float* accum            = (float*)(ws + 0);         // 497664 f
    float* props            = (float*)(ws + 1990656);
    float* boxes            = (float*)(ws + 3317760);
    float* cls2             = (float*)(ws + 4644864);
    float* dval             = (float*)(ws + 5308416);
    unsigned int* hist      = (unsigned int*)(ws + 5640192);
    unsigned int* ctrl      = (unsigned int*)(ws + 5902336);
    unsigned long long* cand = (unsigned long long*)(ws + 5902400);
    float* topBoxes         = (float*)(ws + 5967936);
    float* topProbs         = (float*)(ws + 6063936);
    unsigned long long* mask = (unsigned long long*)(ws + 6087936);  // 4.512 MB
    _Float16* xt_h          = (_Float16*)(ws + 10599936);  // 18.87 MB
    _Float16* xt_l          = (_Float16*)(ws + 29474304);  // 18.87 MB
    _Float16* wt_h          = (_Float16*)(ws + 48348672);  // 9.44 MB
    _Float16* wt_l          = (_Float16*)(ws + 57785856);  // 9.44 MB (ends 67.2 MB)

    float* out0 = (float*)d_out;
    float* out1 = out0 + (size_t)nv * 4;
    float* out2 = out1 + (size_t)nv * 2;
    float* out3 = out2 + (size_t)POSN * 4;

    k_init<<<(NPIX * NCH + 65536 + 16 + 255) / 256, 256, 0, stream>>>(b_cls, b_reg, accum, hist, ctrl);
    k_xtr<<<dim3(144, 16), 256, 0, stream>>>(x, xt_h, xt_l);
    k_wtr<<<2048, 256, 0, stream>>>(w_rpn, wt_h, wt_l);
    k_conv<<<dim3(4, 96), 256, 0, stream>>>(xt_h, xt_l, wt_h, wt_l, b_rpn, w_cls, w_reg, accum);
    k_decode<<<(NA + 255) / 256, 256, 0, stream>>>(accum, anchors, props, boxes, cls2, dval, hist);
    k_thresh<<<1, 256, 0, stream>>>(hist, ctrl);
    k_compact<<<(NA + 255) / 256, 256, 0, stream>>>(dval, ctrl, cand);
    k_sort<<<1, 1024, 0, stream>>>(cand, ctrl, boxes, dval, topBoxes, topProbs);
    k_mask<<<(TOPN * NW + 255) / 256, 256, 0, stream>>>(topBoxes, mask);
    k_scan<<<1, 64, 0, stream>>>(mask, topBoxes, topProbs, out2, out3);
    k_gather<<<(nv + 255) / 256, 256, 0, stream>>>(vidx, props, cls2, out0, out1, nv);
}